// Round 8
// baseline (653.598 us; speedup 1.0000x reference)
//
#include <hip/hip_runtime.h>
#include <hip/hip_bf16.h>

// Problem constants (B=4, S=2048, D=1024, H=16, DK=64)
#define BB 4
#define SS 2048
#define DD 1024
#define HH 16
#define DKK 64

typedef __bf16 bf16x8 __attribute__((ext_vector_type(8)));
typedef float floatx4 __attribute__((ext_vector_type(4)));

#if __has_builtin(__builtin_amdgcn_exp2f)
#define EXP2(x) __builtin_amdgcn_exp2f(x)
#else
#define EXP2(x) exp2f(x)
#endif

__device__ __forceinline__ float b2f(unsigned short u) {
    union { unsigned int i; float f; } c;
    c.i = ((unsigned int)u) << 16;
    return c.f;
}
__device__ __forceinline__ unsigned short f2b(float f) {
    unsigned int i = __float_as_uint(f);
    unsigned int r = (i + 0x7FFFu + ((i >> 16) & 1u)) >> 16;  // RNE
    return (unsigned short)r;
}
// cheap round-half-up bf16 pair pack: (lo, hi) -> u32
__device__ __forceinline__ unsigned int pkpair(float a, float b) {
    unsigned int ia = (__float_as_uint(a) + 0x8000u) >> 16;
    unsigned int ib = (__float_as_uint(b) + 0x8000u) & 0xffff0000u;
    return ia | ib;
}

// async global->LDS, 16 B per lane; LDS dst = wave-uniform base + lane*16
__device__ __forceinline__ void gload_lds16(const unsigned short* g,
                                            unsigned short* l) {
    __builtin_amdgcn_global_load_lds(
        (const __attribute__((address_space(1))) unsigned int*)g,
        (__attribute__((address_space(3))) unsigned int*)l, 16, 0, 0);
}

// ---------------------------------------------------------------------------
// fp32 -> bf16 conversion, 4 elems/thread
// ---------------------------------------------------------------------------
__global__ void cvt_f32_bf16(const float* __restrict__ in,
                             unsigned short* __restrict__ out, int n4) {
    int i = blockIdx.x * blockDim.x + threadIdx.x;
    if (i >= n4) return;
    float4 v = ((const float4*)in)[i];
    ushort4 o;
    o.x = f2b(v.x); o.y = f2b(v.y); o.z = f2b(v.z); o.w = f2b(v.w);
    ((ushort4*)out)[i] = o;
}

// ---------------------------------------------------------------------------
// 128x256 quadrant-phase NT GEMM (round-7, validated) - UNCHANGED.
// This round's cross-session clock reference.
// ---------------------------------------------------------------------------
template <typename CT>
__global__ __launch_bounds__(512, 1) void gemm_nt_128x256(
    const unsigned short* __restrict__ A,
    const unsigned short* __restrict__ B,
    CT* __restrict__ C, int M, int N, int K) {
    extern __shared__ unsigned short lds[];  // 2 x 24576 shorts = 96 KiB

    const int tid  = threadIdx.x;
    const int lane = tid & 63;
    const int w    = tid >> 6;          // 0..7
    const int wmh  = w >> 2;            // 0..1 : M half (64 rows)
    const int wnq  = w & 3;             // 0..3 : 64-col group

    const int m0 = blockIdx.x * 128;
    const int n0 = blockIdx.y * 256;

    const int row16 = lane & 15;
    const int part  = lane >> 4;
    const int rbase = part * 4;
    const int shr   = (row16 & 7) << 3;   // read-side XOR (shorts)

    // staging: thread covers row tid>>3, 16B chunk tid&7, pre-swizzled col
    const int srow = tid >> 3;                             // 0..63
    const int scol = ((tid & 7) * 8) ^ ((srow & 7) << 3);  // shorts
    const unsigned short* Ag = A + (size_t)(m0 + srow) * K + scol;
    const unsigned short* Bg = B + (size_t)(n0 + srow) * K + scol;
    const int ldsw = w * 512;  // wave-uniform LDS stage base within a round

    const int NT = K >> 6;
    floatx4 acc[4][4] = {};

#define STAGE_TILE(t)                                                    \
    {                                                                    \
        unsigned short* sb = lds + ((t) & 1) * 24576;                    \
        const size_t ko = (size_t)(t) * 64;                              \
        _Pragma("unroll") for (int r2 = 0; r2 < 2; ++r2)                 \
            gload_lds16(Ag + (size_t)(r2 * 64) * K + ko,                 \
                        sb + r2 * 4096 + ldsw);                          \
        _Pragma("unroll") for (int r2 = 0; r2 < 4; ++r2)                 \
            gload_lds16(Bg + (size_t)(r2 * 64) * K + ko,                 \
                        sb + 8192 + r2 * 4096 + ldsw);                   \
    }

    STAGE_TILE(0);

    bf16x8 bfr[4][2];  // B-frags for the wave's 64 cols, live whole tile
    for (int kt = 0; kt < NT; ++kt) {
        const unsigned short* Ab = lds + (kt & 1) * 24576;
        const unsigned short* Bb = Ab + 8192;
#pragma unroll
        for (int q = 0; q < 2; ++q) {
            if (q == 0) {
                if (kt + 1 < NT) {
                    STAGE_TILE(kt + 1);
                    asm volatile("s_waitcnt vmcnt(6)" ::: "memory");
                } else {
                    asm volatile("s_waitcnt vmcnt(0)" ::: "memory");
                }
                __builtin_amdgcn_sched_barrier(0);
                __builtin_amdgcn_s_barrier();  // all waves' stage loads
                                               // landed before any reads
#pragma unroll
                for (int j = 0; j < 4; ++j)
#pragma unroll
                    for (int u = 0; u < 2; ++u)
                        bfr[j][u] = *(const bf16x8*)(
                            Bb + (wnq * 64 + j * 16 + row16) * 64 +
                            ((u * 32 + part * 8) ^ shr));
            }
            bf16x8 af[2][2];
#pragma unroll
            for (int i = 0; i < 2; ++i)
#pragma unroll
                for (int u = 0; u < 2; ++u)
                    af[i][u] = *(const bf16x8*)(
                        Ab + (wmh * 64 + (q * 2 + i) * 16 + row16) * 64 +
                        ((u * 32 + part * 8) ^ shr));
            __builtin_amdgcn_s_barrier();
            asm volatile("s_waitcnt lgkmcnt(0)" ::: "memory");
            __builtin_amdgcn_sched_barrier(0);
            __builtin_amdgcn_s_setprio(1);
#pragma unroll
            for (int i = 0; i < 2; ++i)
#pragma unroll
                for (int j = 0; j < 4; ++j)
#pragma unroll
                    for (int u = 0; u < 2; ++u)
                        acc[q * 2 + i][j] =
                            __builtin_amdgcn_mfma_f32_16x16x32_bf16(
                                af[i][u], bfr[j][u], acc[q * 2 + i][j],
                                0, 0, 0);
            __builtin_amdgcn_s_setprio(0);
            __builtin_amdgcn_sched_barrier(0);
            __builtin_amdgcn_s_barrier();
        }
    }
#undef STAGE_TILE

#pragma unroll
    for (int i = 0; i < 4; ++i) {
#pragma unroll
        for (int j = 0; j < 4; ++j) {
            const int row = m0 + wmh * 64 + i * 16 + rbase;
            const int col = n0 + wnq * 64 + j * 16 + row16;
#pragma unroll
            for (int r = 0; r < 4; ++r) {
                size_t idx = (size_t)(row + r) * N + col;
                if constexpr (sizeof(CT) == 2) C[idx] = f2b(acc[i][j][r]);
                else                           C[idx] = acc[i][j][r];
            }
        }
    }
}

// ---------------------------------------------------------------------------
// repack_kv (unchanged): fragment-linear K / V^T tiles per (b,h,stile64).
// ---------------------------------------------------------------------------
__global__ void repack_kv(const unsigned short* __restrict__ qkv,
                          unsigned short* __restrict__ Kp,
                          unsigned short* __restrict__ Vt) {
    __shared__ unsigned short Vs[64][72];
    const int st = blockIdx.x, h = blockIdx.y, b = blockIdx.z;
    const int tid = threadIdx.x;
    const size_t base = ((size_t)((b * HH + h) * (SS / 64) + st)) * 4096;

#pragma unroll
    for (int p = 0; p < 2; ++p) {
        const int row = p * 32 + (tid >> 3);
        const int chunk = tid & 7;
        size_t src = (size_t)(b * SS + st * 64 + row) * (3 * DD) +
                     DD + h * DKK + chunk * 8;
        uint4 kv = *(const uint4*)(qkv + src);
        *(uint4*)(Kp + base + (chunk >> 2) * 2048 + row * 32 + (chunk & 3) * 8) = kv;
        uint4 vv = *(const uint4*)(qkv + src + DD);
        *(uint4*)&Vs[row][chunk * 8] = vv;
    }
    __syncthreads();
#pragma unroll
    for (int p = 0; p < 2; ++p) {
        const int dk = p * 32 + (tid >> 3);
        const int s8 = tid & 7;
        union { unsigned short u[8]; uint4 v; } pk;
#pragma unroll
        for (int j = 0; j < 8; ++j) pk.u[j] = Vs[s8 * 8 + j][dk];
        *(uint4*)(Vt + base + (s8 >> 2) * 2048 + dk * 32 + (s8 & 3) * 8) = pk.v;
    }
}

// ---------------------------------------------------------------------------
// MFMA flash attention v9 (causal): v6 math + defer-max, with the KV RANGE
// SPLIT across 2 waves per strip-pair to double occupancy (grid was the
// limiter: 512 blocks = 2/CU at VGPR 124 which allows 4/CU).
// Front wave: KV tiles [0,c); back wave: [c,ntB). c = ntA>=8 ? 8 : 17-ntA
// gives each wave exactly 16 or 17 tiles for EVERY pair (sum 33). Tile
// ranges are disjoint => zero added K/V traffic; loop body identical to v6
// => same 124-reg pressure. Partial (m,l,O) merged once via LDS:
// l = l0*2^(m0-m) + l1*2^(m1-m), O likewise (exp2(-1e30-m)=0 handles empty
// ranges). Grid 1024 blocks = 4/CU, 4096 waves.
// ---------------------------------------------------------------------------
struct StripState {
    bf16x8 qf[2][2];
    floatx4 O[2][4];
    float mrow[2], lrow[2];
    int q0w;
};

__device__ __forceinline__ void strip_init(
    StripState& S, const unsigned short* __restrict__ qkv,
    int b, int h, int q0w, int row16, int part) {
    const float c1 = 0.180336884f;  // 0.125 * log2(e)
    S.q0w = q0w;
#pragma unroll
    for (int qt = 0; qt < 2; ++qt) {
        S.mrow[qt] = -1e30f;
        S.lrow[qt] = 0.f;
#pragma unroll
        for (int dt = 0; dt < 4; ++dt) S.O[qt][dt] = floatx4{0, 0, 0, 0};
#pragma unroll
        for (int u = 0; u < 2; ++u) {
            const unsigned short* qp = qkv +
                (size_t)(b * SS + q0w + qt * 16 + row16) * (3 * DD) +
                h * DKK + u * 32 + part * 8;
            union { uint4 r; unsigned short us[8]; } raw;
            raw.r = *(const uint4*)qp;
            union { unsigned short us[8]; bf16x8 v; } sq;
#pragma unroll
            for (int j = 0; j < 8; ++j) sq.us[j] = f2b(b2f(raw.us[j]) * c1);
            S.qf[qt][u] = sq.v;
        }
    }
}

__device__ __forceinline__ void strip_tile(
    StripState& S, int k0, const bf16x8 kf[2][4], const bf16x8 vf[2][4],
    int row16, int part, int rbase) {
#pragma unroll
    for (int qt = 0; qt < 2; ++qt) {
        // ---- S^T: lane holds q=row16, s = kt*16 + rbase + r ----
        floatx4 sc[4] = {};
#pragma unroll
        for (int u = 0; u < 2; ++u)
#pragma unroll
            for (int kt = 0; kt < 4; ++kt)
                sc[kt] = __builtin_amdgcn_mfma_f32_16x16x32_bf16(
                    kf[u][kt], S.qf[qt][u], sc[kt], 0, 0, 0);

        const int qa = S.q0w + qt * 16 + row16;
        const bool full = (k0 + 63 <= S.q0w + qt * 16);
        float mx = -1e30f;
#pragma unroll
        for (int kt = 0; kt < 4; ++kt)
#pragma unroll
            for (int r = 0; r < 4; ++r) {
                float s = sc[kt][r];  // log2-scaled via Q
                if (!full) {
                    int ka = k0 + kt * 16 + rbase + r;
                    s = (ka <= qa) ? s : -1e30f;
                }
                sc[kt][r] = s;
                mx = fmaxf(mx, s);
            }
        mx = fmaxf(mx, __shfl_xor(mx, 16));
        mx = fmaxf(mx, __shfl_xor(mx, 32));

        // defer-max (T13): wave-uniform skip of the rescale
        const bool resc = !__all(mx - S.mrow[qt] <= 8.f);
        float mnew = resc ? fmaxf(S.mrow[qt], mx) : S.mrow[qt];

        float ps = 0.f;
        unsigned int pk[4][2];
#pragma unroll
        for (int kt = 0; kt < 4; ++kt) {
            float e0 = EXP2(sc[kt][0] - mnew);
            float e1 = EXP2(sc[kt][1] - mnew);
            float e2 = EXP2(sc[kt][2] - mnew);
            float e3 = EXP2(sc[kt][3] - mnew);
            ps += (e0 + e1) + (e2 + e3);
            pk[kt][0] = pkpair(e0, e1);
            pk[kt][1] = pkpair(e2, e3);
        }
        ps += __shfl_xor(ps, 16);
        ps += __shfl_xor(ps, 32);
        if (resc) {
            float alpha = EXP2(S.mrow[qt] - mnew);
            S.lrow[qt] = S.lrow[qt] * alpha + ps;
            S.mrow[qt] = mnew;
#pragma unroll
            for (int dt = 0; dt < 4; ++dt) S.O[qt][dt] *= alpha;
        } else {
            S.lrow[qt] += ps;
        }

        // ---- P^T B-frags (kt-select AFTER shuffle; dest-part algebra) ----
        const int l0 = row16 + ((part & 1) * 2 + 0) * 16;
        const int l1 = row16 + ((part & 1) * 2 + 1) * 16;
        const bool hi = (part >> 1);
#pragma unroll
        for (int u = 0; u < 2; ++u) {
            unsigned int lo00 = (unsigned int)__shfl((int)pk[2 * u][0], l0);
            unsigned int lo01 = (unsigned int)__shfl((int)pk[2 * u][1], l0);
            unsigned int lo10 = (unsigned int)__shfl((int)pk[2 * u][0], l1);
            unsigned int lo11 = (unsigned int)__shfl((int)pk[2 * u][1], l1);
            unsigned int hi00 = (unsigned int)__shfl((int)pk[2 * u + 1][0], l0);
            unsigned int hi01 = (unsigned int)__shfl((int)pk[2 * u + 1][1], l0);
            unsigned int hi10 = (unsigned int)__shfl((int)pk[2 * u + 1][0], l1);
            unsigned int hi11 = (unsigned int)__shfl((int)pk[2 * u + 1][1], l1);
            union { unsigned int u32[4]; bf16x8 v; } P;
            P.u32[0] = hi ? hi00 : lo00;
            P.u32[1] = hi ? hi01 : lo01;
            P.u32[2] = hi ? hi10 : lo10;
            P.u32[3] = hi ? hi11 : lo11;
#pragma unroll
            for (int dt = 0; dt < 4; ++dt)
                S.O[qt][dt] = __builtin_amdgcn_mfma_f32_16x16x32_bf16(
                    vf[u][dt], P.v, S.O[qt][dt], 0, 0, 0);
        }
    }
}

__device__ __forceinline__ void strip_store(
    StripState& S, unsigned short* __restrict__ heads,
    int b, int h, int row16, int rbase) {
#pragma unroll
    for (int qt = 0; qt < 2; ++qt) {
        float inv = 1.f / S.lrow[qt];
#pragma unroll
        for (int dt = 0; dt < 4; ++dt) {
            ushort4 o4;
            o4.x = f2b(S.O[qt][dt][0] * inv);
            o4.y = f2b(S.O[qt][dt][1] * inv);
            o4.z = f2b(S.O[qt][dt][2] * inv);
            o4.w = f2b(S.O[qt][dt][3] * inv);
            size_t base = (size_t)(b * SS + S.q0w + qt * 16 + row16) * DD +
                          h * DKK + dt * 16 + rbase;
            *(ushort4*)&heads[base] = o4;
        }
    }
}

// dump/merge partial online-softmax state (per lane: 32 O + 2 m + 2 l)
__device__ __forceinline__ void strip_dump(const StripState& S, float* mb) {
#pragma unroll
    for (int qt = 0; qt < 2; ++qt)
#pragma unroll
        for (int dt = 0; dt < 4; ++dt)
            *(floatx4*)&mb[qt * 16 + dt * 4] = S.O[qt][dt];
    mb[32] = S.mrow[0]; mb[33] = S.mrow[1];
    mb[34] = S.lrow[0]; mb[35] = S.lrow[1];
}
__device__ __forceinline__ void strip_merge(StripState& S, const float* mb) {
#pragma unroll
    for (int qt = 0; qt < 2; ++qt) {
        float m1 = mb[32 + qt], l1 = mb[34 + qt];
        float m  = fmaxf(S.mrow[qt], m1);
        float a0 = EXP2(S.mrow[qt] - m);
        float a1 = EXP2(m1 - m);          // = 0 when back range was empty
        S.lrow[qt] = S.lrow[qt] * a0 + l1 * a1;
#pragma unroll
        for (int dt = 0; dt < 4; ++dt) {
            floatx4 o1 = *(const floatx4*)&mb[qt * 16 + dt * 4];
            S.O[qt][dt] = S.O[qt][dt] * a0 + o1 * a1;
        }
        S.mrow[qt] = m;
    }
}

__global__ __launch_bounds__(256, 4) void attn_mfma9(
    const unsigned short* __restrict__ qkv,
    const unsigned short* __restrict__ Kp,
    const unsigned short* __restrict__ Vt,
    unsigned short* __restrict__ heads) {
    __shared__ float mbuf[2][64][76];  // [pair][lane][72 used, 76 stride]

    const int tid  = threadIdx.x;
    const int lane = tid & 63;
    const int w    = tid >> 6;
    const int half = w & 1;   // 0 = front (merger+storer), 1 = back
    const int pidx = w >> 1;  // strip-pair within block (0..1)

    // XCD mapping: 16 blocks of one (b,h) pinned to xcd = bx & 7
    const int bx   = blockIdx.x;              // 0..1023
    const int xcd  = bx & 7;
    const int slot = bx >> 3;                 // 0..127
    const int pair = xcd * 8 + (slot >> 4);   // 0..63 = b*16+h
    const int pblk = slot & 15;               // 0..15
    const int b = pair >> 4, h = pair & 15;

    const int jA  = pblk * 2 + pidx;          // 0..31 (light strip)
    const int jB  = 63 - jA;                  // heavy strip
    const int ntA = jA / 2 + 1;
    const int ntB = jB / 2 + 1;
    // split point: each wave gets exactly 16 or 17 strip-tiles
    const int c   = (ntA >= 8) ? 8 : (17 - ntA);

    const int t0  = half ? c : 0;             // wave's KV tile range [t0,t1)
    const int t1  = half ? ntB : c;
    const int tA1 = half ? ntA : ((c < ntA) ? c : ntA);  // SA when t < tA1

    const int row16 = lane & 15;
    const int part  = lane >> 4;
    const int rbase = part * 4;

    StripState SA, SB;
    strip_init(SA, qkv, b, h, jA * 32, row16, part);
    strip_init(SB, qkv, b, h, jB * 32, row16, part);

    const size_t tb = (size_t)pair * (SS / 64) * 4096;

    for (int t = t0; t < t1; ++t) {
        const int k0 = t * 64;
        const unsigned short* kbase = Kp + tb + (size_t)t * 4096;
        const unsigned short* vbase = Vt + tb + (size_t)t * 4096;
        bf16x8 kf[2][4], vf[2][4];
#pragma unroll
        for (int u = 0; u < 2; ++u)
#pragma unroll
            for (int i = 0; i < 4; ++i) {
                kf[u][i] = *(const bf16x8*)(kbase + u * 2048 +
                                            (i * 16 + row16) * 32 + part * 8);
                vf[u][i] = *(const bf16x8*)(vbase + u * 2048 +
                                            (i * 16 + row16) * 32 + part * 8);
            }
        strip_tile(SB, k0, kf, vf, row16, part, rbase);
        if (t < tA1) strip_tile(SA, k0, kf, vf, row16, part, rbase);
    }

    float* mb = &mbuf[pidx][lane][0];
    if (half) {
        strip_dump(SA, mb);
        strip_dump(SB, mb + 36);
    }
    __syncthreads();
    if (!half) {
        strip_merge(SA, mb);
        strip_merge(SB, mb + 36);
        strip_store(SA, heads, b, h, row16, rbase);
        strip_store(SB, heads, b, h, row16, rbase);
    }
}

// ---------------------------------------------------------------------------
extern "C" void kernel_launch(void* const* d_in, const int* in_sizes, int n_in,
                              void* d_out, int out_size, void* d_ws,
                              size_t ws_size, hipStream_t stream) {
    const float* x    = (const float*)d_in[0];
    const float* Wqkv = (const float*)d_in[1];
    const float* Wo   = (const float*)d_in[2];
    float* out = (float*)d_out;

    const size_t NX  = (size_t)BB * SS * DD;
    const size_t NWQ = (size_t)3 * DD * DD;
    const size_t NWO = (size_t)DD * DD;
    const size_t NKV = (size_t)BB * HH * SS * DKK;

    unsigned short* xb     = (unsigned short*)d_ws;
    unsigned short* wqkvb  = xb + NX;
    unsigned short* wob    = wqkvb + NWQ;
    unsigned short* qkvb   = wob + NWO;
    unsigned short* headsb = qkvb + (size_t)BB * SS * 3 * DD;
    unsigned short* Kp     = headsb + NX;
    unsigned short* Vtp    = Kp + NKV;

    static bool attr_done = false;
    if (!attr_done) {
        hipFuncSetAttribute(
            reinterpret_cast<const void*>(&gemm_nt_128x256<unsigned short>),
            hipFuncAttributeMaxDynamicSharedMemorySize, 98304);
        hipFuncSetAttribute(
            reinterpret_cast<const void*>(&gemm_nt_128x256<float>),
            hipFuncAttributeMaxDynamicSharedMemorySize, 98304);
        attr_done = true;
    }

    cvt_f32_bf16<<<(int)(NX / 4 / 256), 256, 0, stream>>>(x, xb, (int)(NX / 4));
    cvt_f32_bf16<<<(int)(NWQ / 4 / 256), 256, 0, stream>>>(Wqkv, wqkvb, (int)(NWQ / 4));
    cvt_f32_bf16<<<(int)(NWO / 4 / 256), 256, 0, stream>>>(Wo, wob, (int)(NWO / 4));

    // QKV projection: 64 x 12 = 768 blocks = 3 exact rounds at 1 blk/CU
    gemm_nt_128x256<unsigned short><<<dim3(BB * SS / 128, 3 * DD / 256), 512,
                                     98304, stream>>>(xb, wqkvb, qkvb,
                                                      BB * SS, 3 * DD, DD);

    // repack K/V into MFMA-ready fragment-linear tiles
    repack_kv<<<dim3(SS / 64, HH, BB), 256, 0, stream>>>(qkvb, Kp, Vtp);

    // causal MFMA attention (v9: KV-split pairs, 1024 blocks = 4/CU)
    attn_mfma9<<<dim3(1024), 256, 0, stream>>>(qkvb, Kp, Vtp, headsb);

    // output projection: 64 x 4 = 256 blocks = exactly 1 blk/CU
    gemm_nt_128x256<float><<<dim3(BB * SS / 128, DD / 256), 512, 98304,
                             stream>>>(headsb, wob, out, BB * SS, DD, DD);
}

// Round 9
// 414.530 us; speedup vs baseline: 1.5767x; 1.5767x over previous
//
#include <hip/hip_runtime.h>
#include <hip/hip_bf16.h>

// Problem constants (B=4, S=2048, D=1024, H=16, DK=64)
#define BB 4
#define SS 2048
#define DD 1024
#define HH 16
#define DKK 64

typedef __bf16 bf16x8 __attribute__((ext_vector_type(8)));
typedef float floatx4 __attribute__((ext_vector_type(4)));

#if __has_builtin(__builtin_amdgcn_exp2f)
#define EXP2(x) __builtin_amdgcn_exp2f(x)
#else
#define EXP2(x) exp2f(x)
#endif

__device__ __forceinline__ float b2f(unsigned short u) {
    union { unsigned int i; float f; } c;
    c.i = ((unsigned int)u) << 16;
    return c.f;
}
__device__ __forceinline__ unsigned short f2b(float f) {
    unsigned int i = __float_as_uint(f);
    unsigned int r = (i + 0x7FFFu + ((i >> 16) & 1u)) >> 16;  // RNE
    return (unsigned short)r;
}
// cheap round-half-up bf16 pair pack: (lo, hi) -> u32
__device__ __forceinline__ unsigned int pkpair(float a, float b) {
    unsigned int ia = (__float_as_uint(a) + 0x8000u) >> 16;
    unsigned int ib = (__float_as_uint(b) + 0x8000u) & 0xffff0000u;
    return ia | ib;
}

// async global->LDS, 16 B per lane; LDS dst = wave-uniform base + lane*16
__device__ __forceinline__ void gload_lds16(const unsigned short* g,
                                            unsigned short* l) {
    __builtin_amdgcn_global_load_lds(
        (const __attribute__((address_space(1))) unsigned int*)g,
        (__attribute__((address_space(3))) unsigned int*)l, 16, 0, 0);
}

// ---------------------------------------------------------------------------
// fp32 -> bf16 conversion, 4 elems/thread
// ---------------------------------------------------------------------------
__global__ void cvt_f32_bf16(const float* __restrict__ in,
                             unsigned short* __restrict__ out, int n4) {
    int i = blockIdx.x * blockDim.x + threadIdx.x;
    if (i >= n4) return;
    float4 v = ((const float4*)in)[i];
    ushort4 o;
    o.x = f2b(v.x); o.y = f2b(v.y); o.z = f2b(v.z); o.w = f2b(v.w);
    ((ushort4*)out)[i] = o;
}

// ---------------------------------------------------------------------------
// 128x256 quadrant-phase NT GEMM (round-7, validated) - UNCHANGED.
// ---------------------------------------------------------------------------
template <typename CT>
__global__ __launch_bounds__(512, 1) void gemm_nt_128x256(
    const unsigned short* __restrict__ A,
    const unsigned short* __restrict__ B,
    CT* __restrict__ C, int M, int N, int K) {
    extern __shared__ unsigned short lds[];  // 2 x 24576 shorts = 96 KiB

    const int tid  = threadIdx.x;
    const int lane = tid & 63;
    const int w    = tid >> 6;          // 0..7
    const int wmh  = w >> 2;            // 0..1 : M half (64 rows)
    const int wnq  = w & 3;             // 0..3 : 64-col group

    const int m0 = blockIdx.x * 128;
    const int n0 = blockIdx.y * 256;

    const int row16 = lane & 15;
    const int part  = lane >> 4;
    const int rbase = part * 4;
    const int shr   = (row16 & 7) << 3;   // read-side XOR (shorts)

    // staging: thread covers row tid>>3, 16B chunk tid&7, pre-swizzled col
    const int srow = tid >> 3;                             // 0..63
    const int scol = ((tid & 7) * 8) ^ ((srow & 7) << 3);  // shorts
    const unsigned short* Ag = A + (size_t)(m0 + srow) * K + scol;
    const unsigned short* Bg = B + (size_t)(n0 + srow) * K + scol;
    const int ldsw = w * 512;  // wave-uniform LDS stage base within a round

    const int NT = K >> 6;
    floatx4 acc[4][4] = {};

#define STAGE_TILE(t)                                                    \
    {                                                                    \
        unsigned short* sb = lds + ((t) & 1) * 24576;                    \
        const size_t ko = (size_t)(t) * 64;                              \
        _Pragma("unroll") for (int r2 = 0; r2 < 2; ++r2)                 \
            gload_lds16(Ag + (size_t)(r2 * 64) * K + ko,                 \
                        sb + r2 * 4096 + ldsw);                          \
        _Pragma("unroll") for (int r2 = 0; r2 < 4; ++r2)                 \
            gload_lds16(Bg + (size_t)(r2 * 64) * K + ko,                 \
                        sb + 8192 + r2 * 4096 + ldsw);                   \
    }

    STAGE_TILE(0);

    bf16x8 bfr[4][2];  // B-frags for the wave's 64 cols, live whole tile
    for (int kt = 0; kt < NT; ++kt) {
        const unsigned short* Ab = lds + (kt & 1) * 24576;
        const unsigned short* Bb = Ab + 8192;
#pragma unroll
        for (int q = 0; q < 2; ++q) {
            if (q == 0) {
                if (kt + 1 < NT) {
                    STAGE_TILE(kt + 1);
                    asm volatile("s_waitcnt vmcnt(6)" ::: "memory");
                } else {
                    asm volatile("s_waitcnt vmcnt(0)" ::: "memory");
                }
                __builtin_amdgcn_sched_barrier(0);
                __builtin_amdgcn_s_barrier();  // all waves' stage loads
                                               // landed before any reads
#pragma unroll
                for (int j = 0; j < 4; ++j)
#pragma unroll
                    for (int u = 0; u < 2; ++u)
                        bfr[j][u] = *(const bf16x8*)(
                            Bb + (wnq * 64 + j * 16 + row16) * 64 +
                            ((u * 32 + part * 8) ^ shr));
            }
            bf16x8 af[2][2];
#pragma unroll
            for (int i = 0; i < 2; ++i)
#pragma unroll
                for (int u = 0; u < 2; ++u)
                    af[i][u] = *(const bf16x8*)(
                        Ab + (wmh * 64 + (q * 2 + i) * 16 + row16) * 64 +
                        ((u * 32 + part * 8) ^ shr));
            __builtin_amdgcn_s_barrier();
            asm volatile("s_waitcnt lgkmcnt(0)" ::: "memory");
            __builtin_amdgcn_sched_barrier(0);
            __builtin_amdgcn_s_setprio(1);
#pragma unroll
            for (int i = 0; i < 2; ++i)
#pragma unroll
                for (int j = 0; j < 4; ++j)
#pragma unroll
                    for (int u = 0; u < 2; ++u)
                        acc[q * 2 + i][j] =
                            __builtin_amdgcn_mfma_f32_16x16x32_bf16(
                                af[i][u], bfr[j][u], acc[q * 2 + i][j],
                                0, 0, 0);
            __builtin_amdgcn_s_setprio(0);
            __builtin_amdgcn_sched_barrier(0);
            __builtin_amdgcn_s_barrier();
        }
    }
#undef STAGE_TILE

#pragma unroll
    for (int i = 0; i < 4; ++i) {
#pragma unroll
        for (int j = 0; j < 4; ++j) {
            const int row = m0 + wmh * 64 + i * 16 + rbase;
            const int col = n0 + wnq * 64 + j * 16 + row16;
#pragma unroll
            for (int r = 0; r < 4; ++r) {
                size_t idx = (size_t)(row + r) * N + col;
                if constexpr (sizeof(CT) == 2) C[idx] = f2b(acc[i][j][r]);
                else                           C[idx] = acc[i][j][r];
            }
        }
    }
}

// ---------------------------------------------------------------------------
// repack_kv (unchanged): fragment-linear K / V^T tiles per (b,h,stile64).
// ---------------------------------------------------------------------------
__global__ void repack_kv(const unsigned short* __restrict__ qkv,
                          unsigned short* __restrict__ Kp,
                          unsigned short* __restrict__ Vt) {
    __shared__ unsigned short Vs[64][72];
    const int st = blockIdx.x, h = blockIdx.y, b = blockIdx.z;
    const int tid = threadIdx.x;
    const size_t base = ((size_t)((b * HH + h) * (SS / 64) + st)) * 4096;

#pragma unroll
    for (int p = 0; p < 2; ++p) {
        const int row = p * 32 + (tid >> 3);
        const int chunk = tid & 7;
        size_t src = (size_t)(b * SS + st * 64 + row) * (3 * DD) +
                     DD + h * DKK + chunk * 8;
        uint4 kv = *(const uint4*)(qkv + src);
        *(uint4*)(Kp + base + (chunk >> 2) * 2048 + row * 32 + (chunk & 3) * 8) = kv;
        uint4 vv = *(const uint4*)(qkv + src + DD);
        *(uint4*)&Vs[row][chunk * 8] = vv;
    }
    __syncthreads();
#pragma unroll
    for (int p = 0; p < 2; ++p) {
        const int dk = p * 32 + (tid >> 3);
        const int s8 = tid & 7;
        union { unsigned short u[8]; uint4 v; } pk;
#pragma unroll
        for (int j = 0; j < 8; ++j) pk.u[j] = Vs[s8 * 8 + j][dk];
        *(uint4*)(Vt + base + (s8 >> 2) * 2048 + dk * 32 + (s8 & 3) * 8) = pk.v;
    }
}

// ---------------------------------------------------------------------------
// MFMA flash attention v10 (causal): v6 math + defer-max, 3-WAY KV SPLIT.
// One strip-pair (jA, 63-jA) per 192-thread block; wave s handles the
// weight-balanced segment s of the pair's 33-weight tile list (weight 2
// while t<ntA, else 1; boundary a(w) = w<=2*ntA ? (w+1)/2 : w-ntA gives
// 11/11/11 +-1). launch_bounds(192,3): reg cap ~170 > the 124 the body
// needs (the 128 cap of rounds 1/8 spilled - never request 4 waves/SIMD
// for this body). Grid 2048 blocks = 4 blocks/CU (12 waves/CU) = exactly
// 2 rounds. Disjoint KV ranges => no extra K/V traffic. 3 partial states
// merged once via LDS (waves 1,2 dump; wave 0 merges + stores;
// exp2(-1e30 - m) = 0 handles empty-range SA states).
// ---------------------------------------------------------------------------
struct StripState {
    bf16x8 qf[2][2];
    floatx4 O[2][4];
    float mrow[2], lrow[2];
    int q0w;
};

__device__ __forceinline__ void strip_init(
    StripState& S, const unsigned short* __restrict__ qkv,
    int b, int h, int q0w, int row16, int part) {
    const float c1 = 0.180336884f;  // 0.125 * log2(e)
    S.q0w = q0w;
#pragma unroll
    for (int qt = 0; qt < 2; ++qt) {
        S.mrow[qt] = -1e30f;
        S.lrow[qt] = 0.f;
#pragma unroll
        for (int dt = 0; dt < 4; ++dt) S.O[qt][dt] = floatx4{0, 0, 0, 0};
#pragma unroll
        for (int u = 0; u < 2; ++u) {
            const unsigned short* qp = qkv +
                (size_t)(b * SS + q0w + qt * 16 + row16) * (3 * DD) +
                h * DKK + u * 32 + part * 8;
            union { uint4 r; unsigned short us[8]; } raw;
            raw.r = *(const uint4*)qp;
            union { unsigned short us[8]; bf16x8 v; } sq;
#pragma unroll
            for (int j = 0; j < 8; ++j) sq.us[j] = f2b(b2f(raw.us[j]) * c1);
            S.qf[qt][u] = sq.v;
        }
    }
}

__device__ __forceinline__ void strip_tile(
    StripState& S, int k0, const bf16x8 kf[2][4], const bf16x8 vf[2][4],
    int row16, int part, int rbase) {
#pragma unroll
    for (int qt = 0; qt < 2; ++qt) {
        // ---- S^T: lane holds q=row16, s = kt*16 + rbase + r ----
        floatx4 sc[4] = {};
#pragma unroll
        for (int u = 0; u < 2; ++u)
#pragma unroll
            for (int kt = 0; kt < 4; ++kt)
                sc[kt] = __builtin_amdgcn_mfma_f32_16x16x32_bf16(
                    kf[u][kt], S.qf[qt][u], sc[kt], 0, 0, 0);

        const int qa = S.q0w + qt * 16 + row16;
        const bool full = (k0 + 63 <= S.q0w + qt * 16);
        float mx = -1e30f;
#pragma unroll
        for (int kt = 0; kt < 4; ++kt)
#pragma unroll
            for (int r = 0; r < 4; ++r) {
                float s = sc[kt][r];  // log2-scaled via Q
                if (!full) {
                    int ka = k0 + kt * 16 + rbase + r;
                    s = (ka <= qa) ? s : -1e30f;
                }
                sc[kt][r] = s;
                mx = fmaxf(mx, s);
            }
        mx = fmaxf(mx, __shfl_xor(mx, 16));
        mx = fmaxf(mx, __shfl_xor(mx, 32));

        // defer-max (T13): wave-uniform skip of the rescale
        const bool resc = !__all(mx - S.mrow[qt] <= 8.f);
        float mnew = resc ? fmaxf(S.mrow[qt], mx) : S.mrow[qt];

        float ps = 0.f;
        unsigned int pk[4][2];
#pragma unroll
        for (int kt = 0; kt < 4; ++kt) {
            float e0 = EXP2(sc[kt][0] - mnew);
            float e1 = EXP2(sc[kt][1] - mnew);
            float e2 = EXP2(sc[kt][2] - mnew);
            float e3 = EXP2(sc[kt][3] - mnew);
            ps += (e0 + e1) + (e2 + e3);
            pk[kt][0] = pkpair(e0, e1);
            pk[kt][1] = pkpair(e2, e3);
        }
        ps += __shfl_xor(ps, 16);
        ps += __shfl_xor(ps, 32);
        if (resc) {
            float alpha = EXP2(S.mrow[qt] - mnew);
            S.lrow[qt] = S.lrow[qt] * alpha + ps;
            S.mrow[qt] = mnew;
#pragma unroll
            for (int dt = 0; dt < 4; ++dt) S.O[qt][dt] *= alpha;
        } else {
            S.lrow[qt] += ps;
        }

        // ---- P^T B-frags (kt-select AFTER shuffle; dest-part algebra) ----
        const int l0 = row16 + ((part & 1) * 2 + 0) * 16;
        const int l1 = row16 + ((part & 1) * 2 + 1) * 16;
        const bool hi = (part >> 1);
#pragma unroll
        for (int u = 0; u < 2; ++u) {
            unsigned int lo00 = (unsigned int)__shfl((int)pk[2 * u][0], l0);
            unsigned int lo01 = (unsigned int)__shfl((int)pk[2 * u][1], l0);
            unsigned int lo10 = (unsigned int)__shfl((int)pk[2 * u][0], l1);
            unsigned int lo11 = (unsigned int)__shfl((int)pk[2 * u][1], l1);
            unsigned int hi00 = (unsigned int)__shfl((int)pk[2 * u + 1][0], l0);
            unsigned int hi01 = (unsigned int)__shfl((int)pk[2 * u + 1][1], l0);
            unsigned int hi10 = (unsigned int)__shfl((int)pk[2 * u + 1][0], l1);
            unsigned int hi11 = (unsigned int)__shfl((int)pk[2 * u + 1][1], l1);
            union { unsigned int u32[4]; bf16x8 v; } P;
            P.u32[0] = hi ? hi00 : lo00;
            P.u32[1] = hi ? hi01 : lo01;
            P.u32[2] = hi ? hi10 : lo10;
            P.u32[3] = hi ? hi11 : lo11;
#pragma unroll
            for (int dt = 0; dt < 4; ++dt)
                S.O[qt][dt] = __builtin_amdgcn_mfma_f32_16x16x32_bf16(
                    vf[u][dt], P.v, S.O[qt][dt], 0, 0, 0);
        }
    }
}

__device__ __forceinline__ void strip_store(
    StripState& S, unsigned short* __restrict__ heads,
    int b, int h, int row16, int rbase) {
#pragma unroll
    for (int qt = 0; qt < 2; ++qt) {
        float inv = 1.f / S.lrow[qt];
#pragma unroll
        for (int dt = 0; dt < 4; ++dt) {
            ushort4 o4;
            o4.x = f2b(S.O[qt][dt][0] * inv);
            o4.y = f2b(S.O[qt][dt][1] * inv);
            o4.z = f2b(S.O[qt][dt][2] * inv);
            o4.w = f2b(S.O[qt][dt][3] * inv);
            size_t base = (size_t)(b * SS + S.q0w + qt * 16 + row16) * DD +
                          h * DKK + dt * 16 + rbase;
            *(ushort4*)&heads[base] = o4;
        }
    }
}

// dump/merge partial online-softmax state (per lane: 32 O + 2 m + 2 l)
__device__ __forceinline__ void strip_dump(const StripState& S, float* mb) {
#pragma unroll
    for (int qt = 0; qt < 2; ++qt)
#pragma unroll
        for (int dt = 0; dt < 4; ++dt)
            *(floatx4*)&mb[qt * 16 + dt * 4] = S.O[qt][dt];
    mb[32] = S.mrow[0]; mb[33] = S.mrow[1];
    mb[34] = S.lrow[0]; mb[35] = S.lrow[1];
}
__device__ __forceinline__ void strip_merge(StripState& S, const float* mb) {
#pragma unroll
    for (int qt = 0; qt < 2; ++qt) {
        float m1 = mb[32 + qt], l1 = mb[34 + qt];
        float m  = fmaxf(S.mrow[qt], m1);
        float a0 = EXP2(S.mrow[qt] - m);
        float a1 = EXP2(m1 - m);          // = 0 when that range was empty
        S.lrow[qt] = S.lrow[qt] * a0 + l1 * a1;
#pragma unroll
        for (int dt = 0; dt < 4; ++dt) {
            floatx4 o1 = *(const floatx4*)&mb[qt * 16 + dt * 4];
            S.O[qt][dt] = S.O[qt][dt] * a0 + o1 * a1;
        }
        S.mrow[qt] = m;
    }
}

__global__ __launch_bounds__(192, 3) void attn_mfma10(
    const unsigned short* __restrict__ qkv,
    const unsigned short* __restrict__ Kp,
    const unsigned short* __restrict__ Vt,
    unsigned short* __restrict__ heads) {
    __shared__ float mbuf[2][64][76];  // [dump slot][lane][72 used]

    const int tid  = threadIdx.x;
    const int lane = tid & 63;
    const int w    = tid >> 6;                // 0..2 : KV segment

    // XCD mapping: 32 blocks of one (b,h) pinned to xcd = bx & 7
    const int bx   = blockIdx.x;              // 0..2047
    const int xcd  = bx & 7;
    const int slot = bx >> 3;                 // 0..255
    const int pair = xcd * 8 + (slot >> 5);   // 0..63 = b*16+h
    const int jA   = slot & 31;               // 0..31 (light strip)
    const int b = pair >> 4, h = pair & 15;

    const int jB  = 63 - jA;                  // heavy strip
    const int ntA = jA / 2 + 1;
    const int ntB = jB / 2 + 1;               // ntA + ntB = 33 (weight)
    // weight-balanced 3-way boundaries (weight 2 for t<ntA, else 1)
    const int a1 = (11 <= 2 * ntA) ? 6 : (11 - ntA);
    const int a2 = (22 <= 2 * ntA) ? 11 : (22 - ntA);
    const int t0 = (w == 0) ? 0 : ((w == 1) ? a1 : a2);
    const int t1 = (w == 0) ? a1 : ((w == 1) ? a2 : ntB);

    const int row16 = lane & 15;
    const int part  = lane >> 4;
    const int rbase = part * 4;

    StripState SA, SB;
    strip_init(SA, qkv, b, h, jA * 32, row16, part);
    strip_init(SB, qkv, b, h, jB * 32, row16, part);

    const size_t tb = (size_t)pair * (SS / 64) * 4096;

    for (int t = t0; t < t1; ++t) {
        const int k0 = t * 64;
        const unsigned short* kbase = Kp + tb + (size_t)t * 4096;
        const unsigned short* vbase = Vt + tb + (size_t)t * 4096;
        bf16x8 kf[2][4], vf[2][4];
#pragma unroll
        for (int u = 0; u < 2; ++u)
#pragma unroll
            for (int i = 0; i < 4; ++i) {
                kf[u][i] = *(const bf16x8*)(kbase + u * 2048 +
                                            (i * 16 + row16) * 32 + part * 8);
                vf[u][i] = *(const bf16x8*)(vbase + u * 2048 +
                                            (i * 16 + row16) * 32 + part * 8);
            }
        strip_tile(SB, k0, kf, vf, row16, part, rbase);
        if (t < ntA) strip_tile(SA, k0, kf, vf, row16, part, rbase);
    }

    if (w > 0) {
        float* mb = &mbuf[w - 1][lane][0];
        strip_dump(SA, mb);
        strip_dump(SB, mb + 36);
    }
    __syncthreads();
    if (w == 0) {
#pragma unroll
        for (int s = 0; s < 2; ++s) {
            const float* mb = &mbuf[s][lane][0];
            strip_merge(SA, mb);
            strip_merge(SB, mb + 36);
        }
        strip_store(SA, heads, b, h, row16, rbase);
        strip_store(SB, heads, b, h, row16, rbase);
    }
}

// ---------------------------------------------------------------------------
extern "C" void kernel_launch(void* const* d_in, const int* in_sizes, int n_in,
                              void* d_out, int out_size, void* d_ws,
                              size_t ws_size, hipStream_t stream) {
    const float* x    = (const float*)d_in[0];
    const float* Wqkv = (const float*)d_in[1];
    const float* Wo   = (const float*)d_in[2];
    float* out = (float*)d_out;

    const size_t NX  = (size_t)BB * SS * DD;
    const size_t NWQ = (size_t)3 * DD * DD;
    const size_t NWO = (size_t)DD * DD;
    const size_t NKV = (size_t)BB * HH * SS * DKK;

    unsigned short* xb     = (unsigned short*)d_ws;
    unsigned short* wqkvb  = xb + NX;
    unsigned short* wob    = wqkvb + NWQ;
    unsigned short* qkvb   = wob + NWO;
    unsigned short* headsb = qkvb + (size_t)BB * SS * 3 * DD;
    unsigned short* Kp     = headsb + NX;
    unsigned short* Vtp    = Kp + NKV;

    static bool attr_done = false;
    if (!attr_done) {
        hipFuncSetAttribute(
            reinterpret_cast<const void*>(&gemm_nt_128x256<unsigned short>),
            hipFuncAttributeMaxDynamicSharedMemorySize, 98304);
        hipFuncSetAttribute(
            reinterpret_cast<const void*>(&gemm_nt_128x256<float>),
            hipFuncAttributeMaxDynamicSharedMemorySize, 98304);
        attr_done = true;
    }

    cvt_f32_bf16<<<(int)(NX / 4 / 256), 256, 0, stream>>>(x, xb, (int)(NX / 4));
    cvt_f32_bf16<<<(int)(NWQ / 4 / 256), 256, 0, stream>>>(Wqkv, wqkvb, (int)(NWQ / 4));
    cvt_f32_bf16<<<(int)(NWO / 4 / 256), 256, 0, stream>>>(Wo, wob, (int)(NWO / 4));

    // QKV projection: 64 x 12 = 768 blocks = 3 exact rounds at 1 blk/CU
    gemm_nt_128x256<unsigned short><<<dim3(BB * SS / 128, 3 * DD / 256), 512,
                                     98304, stream>>>(xb, wqkvb, qkvb,
                                                      BB * SS, 3 * DD, DD);

    // repack K/V into MFMA-ready fragment-linear tiles
    repack_kv<<<dim3(SS / 64, HH, BB), 256, 0, stream>>>(qkvb, Kp, Vtp);

    // causal MFMA attention (v10: 3-way KV split, 2048 blocks = 2 rounds)
    attn_mfma10<<<dim3(2048), 192, 0, stream>>>(qkvb, Kp, Vtp, headsb);

    // output projection: 64 x 4 = 256 blocks = exactly 1 blk/CU
    gemm_nt_128x256<float><<<dim3(BB * SS / 128, DD / 256), 512, 98304,
                             stream>>>(headsb, wob, out, BB * SS, DD, DD);
}

// Round 11
// 260.967 us; speedup vs baseline: 2.5045x; 1.5884x over previous
//
#include <hip/hip_runtime.h>
#include <hip/hip_bf16.h>

// Problem constants (B=4, S=2048, D=1024, H=16, DK=64)
#define BB 4
#define SS 2048
#define DD 1024
#define HH 16
#define DKK 64

typedef __bf16 bf16x8 __attribute__((ext_vector_type(8)));
typedef float floatx4 __attribute__((ext_vector_type(4)));

#if __has_builtin(__builtin_amdgcn_exp2f)
#define EXP2(x) __builtin_amdgcn_exp2f(x)
#else
#define EXP2(x) exp2f(x)
#endif

__device__ __forceinline__ float b2f(unsigned short u) {
    union { unsigned int i; float f; } c;
    c.i = ((unsigned int)u) << 16;
    return c.f;
}
__device__ __forceinline__ unsigned short f2b(float f) {
    unsigned int i = __float_as_uint(f);
    unsigned int r = (i + 0x7FFFu + ((i >> 16) & 1u)) >> 16;  // RNE
    return (unsigned short)r;
}
// cheap round-half-up bf16 pair pack: (lo, hi) -> u32
__device__ __forceinline__ unsigned int pkpair(float a, float b) {
    unsigned int ia = (__float_as_uint(a) + 0x8000u) >> 16;
    unsigned int ib = (__float_as_uint(b) + 0x8000u) & 0xffff0000u;
    return ia | ib;
}

// async global->LDS, 16 B per lane; LDS dst = wave-uniform base + lane*16
__device__ __forceinline__ void gload_lds16(const unsigned short* g,
                                            unsigned short* l) {
    __builtin_amdgcn_global_load_lds(
        (const __attribute__((address_space(1))) unsigned int*)g,
        (__attribute__((address_space(3))) unsigned int*)l, 16, 0, 0);
}

// ---------------------------------------------------------------------------
// fp32 -> bf16 conversion for all three inputs in ONE dispatch
// (x | W_qkv | W_o), 4 elems/thread. Saves two launch overheads vs three
// separate dispatches; per-element math identical.
// ---------------------------------------------------------------------------
__global__ void cvt_all(const float* __restrict__ x,
                        const float* __restrict__ wq,
                        const float* __restrict__ wo,
                        unsigned short* __restrict__ xb,
                        unsigned short* __restrict__ wqb,
                        unsigned short* __restrict__ wob,
                        int n0, int n1, int n2) {
    int i = blockIdx.x * blockDim.x + threadIdx.x;
    const float* src;
    unsigned short* dst;
    int k;
    if (i < n0) {
        src = x; dst = xb; k = i;
    } else if (i < n0 + n1) {
        src = wq; dst = wqb; k = i - n0;
    } else if (i < n0 + n1 + n2) {
        src = wo; dst = wob; k = i - n0 - n1;
    } else {
        return;
    }
    float4 v = ((const float4*)src)[k];
    ushort4 o;
    o.x = f2b(v.x); o.y = f2b(v.y); o.z = f2b(v.z); o.w = f2b(v.w);
    ((ushort4*)dst)[k] = o;
}

// ---------------------------------------------------------------------------
// 128x256 quadrant-phase NT GEMM (round-7, validated green twice).
// BK=64, 512 threads = 8 waves as 2M x 4N, per-wave output 64x64
// (acc[4][4]); per K-tile 2 phases of 16 MFMA. ds_read:MFMA = 12:32.
// LDS 96 KiB = 2 slots x (A 128x64 + B 256x64) bf16, XOR-swizzle
// (shorts col ^= (row&7)<<3) on both sides.
// Counted vmcnt: whole-tile stage (6 gloads/wave) at q0; vmcnt(6) at the
// next tile's q0 waits only for loads issued 2 phases earlier.
// Race discipline: stage -> vmcnt -> s_barrier -> ds_reads.
// ---------------------------------------------------------------------------
template <typename CT>
__global__ __launch_bounds__(512, 1) void gemm_nt_128x256(
    const unsigned short* __restrict__ A,
    const unsigned short* __restrict__ B,
    CT* __restrict__ C, int M, int N, int K) {
    extern __shared__ unsigned short lds[];  // 2 x 24576 shorts = 96 KiB

    const int tid  = threadIdx.x;
    const int lane = tid & 63;
    const int w    = tid >> 6;          // 0..7
    const int wmh  = w >> 2;            // 0..1 : M half (64 rows)
    const int wnq  = w & 3;             // 0..3 : 64-col group

    const int m0 = blockIdx.x * 128;
    const int n0 = blockIdx.y * 256;

    const int row16 = lane & 15;
    const int part  = lane >> 4;
    const int rbase = part * 4;
    const int shr   = (row16 & 7) << 3;   // read-side XOR (shorts)

    // staging: thread covers row tid>>3, 16B chunk tid&7, pre-swizzled col
    const int srow = tid >> 3;                             // 0..63
    const int scol = ((tid & 7) * 8) ^ ((srow & 7) << 3);  // shorts
    const unsigned short* Ag = A + (size_t)(m0 + srow) * K + scol;
    const unsigned short* Bg = B + (size_t)(n0 + srow) * K + scol;
    const int ldsw = w * 512;  // wave-uniform LDS stage base within a round

    const int NT = K >> 6;
    floatx4 acc[4][4] = {};

#define STAGE_TILE(t)                                                    \
    {                                                                    \
        unsigned short* sb = lds + ((t) & 1) * 24576;                    \
        const size_t ko = (size_t)(t) * 64;                              \
        _Pragma("unroll") for (int r2 = 0; r2 < 2; ++r2)                 \
            gload_lds16(Ag + (size_t)(r2 * 64) * K + ko,                 \
                        sb + r2 * 4096 + ldsw);                          \
        _Pragma("unroll") for (int r2 = 0; r2 < 4; ++r2)                 \
            gload_lds16(Bg + (size_t)(r2 * 64) * K + ko,                 \
                        sb + 8192 + r2 * 4096 + ldsw);                   \
    }

    STAGE_TILE(0);

    bf16x8 bfr[4][2];  // B-frags for the wave's 64 cols, live whole tile
    for (int kt = 0; kt < NT; ++kt) {
        const unsigned short* Ab = lds + (kt & 1) * 24576;
        const unsigned short* Bb = Ab + 8192;
#pragma unroll
        for (int q = 0; q < 2; ++q) {
            if (q == 0) {
                if (kt + 1 < NT) {
                    STAGE_TILE(kt + 1);
                    asm volatile("s_waitcnt vmcnt(6)" ::: "memory");
                } else {
                    asm volatile("s_waitcnt vmcnt(0)" ::: "memory");
                }
                __builtin_amdgcn_sched_barrier(0);
                __builtin_amdgcn_s_barrier();  // all waves' stage loads
                                               // landed before any reads
#pragma unroll
                for (int j = 0; j < 4; ++j)
#pragma unroll
                    for (int u = 0; u < 2; ++u)
                        bfr[j][u] = *(const bf16x8*)(
                            Bb + (wnq * 64 + j * 16 + row16) * 64 +
                            ((u * 32 + part * 8) ^ shr));
            }
            bf16x8 af[2][2];
#pragma unroll
            for (int i = 0; i < 2; ++i)
#pragma unroll
                for (int u = 0; u < 2; ++u)
                    af[i][u] = *(const bf16x8*)(
                        Ab + (wmh * 64 + (q * 2 + i) * 16 + row16) * 64 +
                        ((u * 32 + part * 8) ^ shr));
            __builtin_amdgcn_s_barrier();
            asm volatile("s_waitcnt lgkmcnt(0)" ::: "memory");
            __builtin_amdgcn_sched_barrier(0);
            __builtin_amdgcn_s_setprio(1);
#pragma unroll
            for (int i = 0; i < 2; ++i)
#pragma unroll
                for (int j = 0; j < 4; ++j)
#pragma unroll
                    for (int u = 0; u < 2; ++u)
                        acc[q * 2 + i][j] =
                            __builtin_amdgcn_mfma_f32_16x16x32_bf16(
                                af[i][u], bfr[j][u], acc[q * 2 + i][j],
                                0, 0, 0);
            __builtin_amdgcn_s_setprio(0);
            __builtin_amdgcn_sched_barrier(0);
            __builtin_amdgcn_s_barrier();
        }
    }
#undef STAGE_TILE

#pragma unroll
    for (int i = 0; i < 4; ++i) {
#pragma unroll
        for (int j = 0; j < 4; ++j) {
            const int row = m0 + wmh * 64 + i * 16 + rbase;
            const int col = n0 + wnq * 64 + j * 16 + row16;
#pragma unroll
            for (int r = 0; r < 4; ++r) {
                size_t idx = (size_t)(row + r) * N + col;
                if constexpr (sizeof(CT) == 2) C[idx] = f2b(acc[i][j][r]);
                else                           C[idx] = acc[i][j][r];
            }
        }
    }
}

// ---------------------------------------------------------------------------
// repack_kv (validated through 8 green rounds): fragment-linear K / V^T
// tiles per (b,h,stile64). The fused-epilogue replacement (round 10)
// produced nondeterministic post-timing output; reverted.
// ---------------------------------------------------------------------------
__global__ void repack_kv(const unsigned short* __restrict__ qkv,
                          unsigned short* __restrict__ Kp,
                          unsigned short* __restrict__ Vt) {
    __shared__ unsigned short Vs[64][72];
    const int st = blockIdx.x, h = blockIdx.y, b = blockIdx.z;
    const int tid = threadIdx.x;
    const size_t base = ((size_t)((b * HH + h) * (SS / 64) + st)) * 4096;

#pragma unroll
    for (int p = 0; p < 2; ++p) {
        const int row = p * 32 + (tid >> 3);
        const int chunk = tid & 7;
        size_t src = (size_t)(b * SS + st * 64 + row) * (3 * DD) +
                     DD + h * DKK + chunk * 8;
        uint4 kv = *(const uint4*)(qkv + src);
        *(uint4*)(Kp + base + (chunk >> 2) * 2048 + row * 32 + (chunk & 3) * 8) = kv;
        uint4 vv = *(const uint4*)(qkv + src + DD);
        *(uint4*)&Vs[row][chunk * 8] = vv;
    }
    __syncthreads();
#pragma unroll
    for (int p = 0; p < 2; ++p) {
        const int dk = p * 32 + (tid >> 3);
        const int s8 = tid & 7;
        union { unsigned short u[8]; uint4 v; } pk;
#pragma unroll
        for (int j = 0; j < 8; ++j) pk.u[j] = Vs[s8 * 8 + j][dk];
        *(uint4*)(Vt + base + (s8 >> 2) * 2048 + dk * 32 + (s8 & 3) * 8) = pk.v;
    }
}

// ---------------------------------------------------------------------------
// MFMA flash attention v6 + defer-max - UNCHANGED (green four rounds).
// Register rule (rounds 1/8/9): the 2-StripState body needs ~220-230 unified
// regs; it fits ONLY at 2 waves/SIMD. Never cap below 256 regs.
// ---------------------------------------------------------------------------
struct StripState {
    bf16x8 qf[2][2];
    floatx4 O[2][4];
    float mrow[2], lrow[2];
    int q0w;
};

__device__ __forceinline__ void strip_init(
    StripState& S, const unsigned short* __restrict__ qkv,
    int b, int h, int q0w, int row16, int part) {
    const float c1 = 0.180336884f;  // 0.125 * log2(e)
    S.q0w = q0w;
#pragma unroll
    for (int qt = 0; qt < 2; ++qt) {
        S.mrow[qt] = -1e30f;
        S.lrow[qt] = 0.f;
#pragma unroll
        for (int dt = 0; dt < 4; ++dt) S.O[qt][dt] = floatx4{0, 0, 0, 0};
#pragma unroll
        for (int u = 0; u < 2; ++u) {
            const unsigned short* qp = qkv +
                (size_t)(b * SS + q0w + qt * 16 + row16) * (3 * DD) +
                h * DKK + u * 32 + part * 8;
            union { uint4 r; unsigned short us[8]; } raw;
            raw.r = *(const uint4*)qp;
            union { unsigned short us[8]; bf16x8 v; } sq;
#pragma unroll
            for (int j = 0; j < 8; ++j) sq.us[j] = f2b(b2f(raw.us[j]) * c1);
            S.qf[qt][u] = sq.v;
        }
    }
}

__device__ __forceinline__ void strip_tile(
    StripState& S, int k0, const bf16x8 kf[2][4], const bf16x8 vf[2][4],
    int row16, int part, int rbase) {
#pragma unroll
    for (int qt = 0; qt < 2; ++qt) {
        // ---- S^T: lane holds q=row16, s = kt*16 + rbase + r ----
        floatx4 sc[4] = {};
#pragma unroll
        for (int u = 0; u < 2; ++u)
#pragma unroll
            for (int kt = 0; kt < 4; ++kt)
                sc[kt] = __builtin_amdgcn_mfma_f32_16x16x32_bf16(
                    kf[u][kt], S.qf[qt][u], sc[kt], 0, 0, 0);

        const int qa = S.q0w + qt * 16 + row16;
        const bool full = (k0 + 63 <= S.q0w + qt * 16);
        float mx = -1e30f;
#pragma unroll
        for (int kt = 0; kt < 4; ++kt)
#pragma unroll
            for (int r = 0; r < 4; ++r) {
                float s = sc[kt][r];  // log2-scaled via Q
                if (!full) {
                    int ka = k0 + kt * 16 + rbase + r;
                    s = (ka <= qa) ? s : -1e30f;
                }
                sc[kt][r] = s;
                mx = fmaxf(mx, s);
            }
        mx = fmaxf(mx, __shfl_xor(mx, 16));
        mx = fmaxf(mx, __shfl_xor(mx, 32));

        // defer-max (T13): wave-uniform skip of the rescale
        const bool resc = !__all(mx - S.mrow[qt] <= 8.f);
        float mnew = resc ? fmaxf(S.mrow[qt], mx) : S.mrow[qt];

        float ps = 0.f;
        unsigned int pk[4][2];
#pragma unroll
        for (int kt = 0; kt < 4; ++kt) {
            float e0 = EXP2(sc[kt][0] - mnew);
            float e1 = EXP2(sc[kt][1] - mnew);
            float e2 = EXP2(sc[kt][2] - mnew);
            float e3 = EXP2(sc[kt][3] - mnew);
            ps += (e0 + e1) + (e2 + e3);
            pk[kt][0] = pkpair(e0, e1);
            pk[kt][1] = pkpair(e2, e3);
        }
        ps += __shfl_xor(ps, 16);
        ps += __shfl_xor(ps, 32);
        if (resc) {
            float alpha = EXP2(S.mrow[qt] - mnew);
            S.lrow[qt] = S.lrow[qt] * alpha + ps;
            S.mrow[qt] = mnew;
#pragma unroll
            for (int dt = 0; dt < 4; ++dt) S.O[qt][dt] *= alpha;
        } else {
            S.lrow[qt] += ps;
        }

        // ---- P^T B-frags (kt-select AFTER shuffle; dest-part algebra) ----
        const int l0 = row16 + ((part & 1) * 2 + 0) * 16;
        const int l1 = row16 + ((part & 1) * 2 + 1) * 16;
        const bool hi = (part >> 1);
#pragma unroll
        for (int u = 0; u < 2; ++u) {
            unsigned int lo00 = (unsigned int)__shfl((int)pk[2 * u][0], l0);
            unsigned int lo01 = (unsigned int)__shfl((int)pk[2 * u][1], l0);
            unsigned int lo10 = (unsigned int)__shfl((int)pk[2 * u][0], l1);
            unsigned int lo11 = (unsigned int)__shfl((int)pk[2 * u][1], l1);
            unsigned int hi00 = (unsigned int)__shfl((int)pk[2 * u + 1][0], l0);
            unsigned int hi01 = (unsigned int)__shfl((int)pk[2 * u + 1][1], l0);
            unsigned int hi10 = (unsigned int)__shfl((int)pk[2 * u + 1][0], l1);
            unsigned int hi11 = (unsigned int)__shfl((int)pk[2 * u + 1][1], l1);
            union { unsigned int u32[4]; bf16x8 v; } P;
            P.u32[0] = hi ? hi00 : lo00;
            P.u32[1] = hi ? hi01 : lo01;
            P.u32[2] = hi ? hi10 : lo10;
            P.u32[3] = hi ? hi11 : lo11;
#pragma unroll
            for (int dt = 0; dt < 4; ++dt)
                S.O[qt][dt] = __builtin_amdgcn_mfma_f32_16x16x32_bf16(
                    vf[u][dt], P.v, S.O[qt][dt], 0, 0, 0);
        }
    }
}

__device__ __forceinline__ void strip_store(
    StripState& S, unsigned short* __restrict__ heads,
    int b, int h, int row16, int rbase) {
#pragma unroll
    for (int qt = 0; qt < 2; ++qt) {
        float inv = 1.f / S.lrow[qt];
#pragma unroll
        for (int dt = 0; dt < 4; ++dt) {
            ushort4 o4;
            o4.x = f2b(S.O[qt][dt][0] * inv);
            o4.y = f2b(S.O[qt][dt][1] * inv);
            o4.z = f2b(S.O[qt][dt][2] * inv);
            o4.w = f2b(S.O[qt][dt][3] * inv);
            size_t base = (size_t)(b * SS + S.q0w + qt * 16 + row16) * DD +
                          h * DKK + dt * 16 + rbase;
            *(ushort4*)&heads[base] = o4;
        }
    }
}

__global__ __launch_bounds__(256, 2) void attn_mfma6(
    const unsigned short* __restrict__ qkv,
    const unsigned short* __restrict__ Kp,
    const unsigned short* __restrict__ Vt,
    unsigned short* __restrict__ heads) {
    const int tid  = threadIdx.x;
    const int lane = tid & 63;
    const int w    = tid >> 6;

    // XCD mapping: 8 blocks of one (b,h) pinned to xcd = bx & 7
    const int bx   = blockIdx.x;              // 0..511
    const int xcd  = bx & 7;
    const int slot = bx >> 3;                 // 0..63
    const int pair = xcd * 8 + (slot >> 3);   // 0..63 = b*16+h
    const int blk  = slot & 7;                // 0..7
    const int b = pair >> 4, h = pair & 15;

    const int jA = blk * 4 + w;               // 0..31 (light strip)
    const int jB = 63 - jA;                   // 32..63 (heavy strip)
    const int ntA = jA / 2 + 1;               // tiles for strip A
    const int ntB = jB / 2 + 1;               // tiles for strip B (>= 17)

    const int row16 = lane & 15;
    const int part  = lane >> 4;
    const int rbase = part * 4;

    StripState SA, SB;
    strip_init(SA, qkv, b, h, jA * 32, row16, part);
    strip_init(SB, qkv, b, h, jB * 32, row16, part);

    const size_t tb = (size_t)pair * (SS / 64) * 4096;

    for (int t = 0; t < ntB; ++t) {
        const int k0 = t * 64;
        const unsigned short* kbase = Kp + tb + (size_t)t * 4096;
        const unsigned short* vbase = Vt + tb + (size_t)t * 4096;
        bf16x8 kf[2][4], vf[2][4];
#pragma unroll
        for (int u = 0; u < 2; ++u)
#pragma unroll
            for (int i = 0; i < 4; ++i) {
                kf[u][i] = *(const bf16x8*)(kbase + u * 2048 +
                                            (i * 16 + row16) * 32 + part * 8);
                vf[u][i] = *(const bf16x8*)(vbase + u * 2048 +
                                            (i * 16 + row16) * 32 + part * 8);
            }
        strip_tile(SB, k0, kf, vf, row16, part, rbase);
        if (t < ntA) strip_tile(SA, k0, kf, vf, row16, part, rbase);
    }

    strip_store(SA, heads, b, h, row16, rbase);
    strip_store(SB, heads, b, h, row16, rbase);
}

// ---------------------------------------------------------------------------
extern "C" void kernel_launch(void* const* d_in, const int* in_sizes, int n_in,
                              void* d_out, int out_size, void* d_ws,
                              size_t ws_size, hipStream_t stream) {
    const float* x    = (const float*)d_in[0];
    const float* Wqkv = (const float*)d_in[1];
    const float* Wo   = (const float*)d_in[2];
    float* out = (float*)d_out;

    const size_t NX  = (size_t)BB * SS * DD;
    const size_t NWQ = (size_t)3 * DD * DD;
    const size_t NWO = (size_t)DD * DD;
    const size_t NKV = (size_t)BB * HH * SS * DKK;

    unsigned short* xb     = (unsigned short*)d_ws;
    unsigned short* wqkvb  = xb + NX;
    unsigned short* wob    = wqkvb + NWQ;
    unsigned short* qkvb   = wob + NWO;
    unsigned short* headsb = qkvb + (size_t)BB * SS * 3 * DD;
    unsigned short* Kp     = headsb + NX;
    unsigned short* Vtp    = Kp + NKV;

    // Unconditional (no call-count branching): cheap host-side calls.
    hipFuncSetAttribute(
        reinterpret_cast<const void*>(&gemm_nt_128x256<unsigned short>),
        hipFuncAttributeMaxDynamicSharedMemorySize, 98304);
    hipFuncSetAttribute(
        reinterpret_cast<const void*>(&gemm_nt_128x256<float>),
        hipFuncAttributeMaxDynamicSharedMemorySize, 98304);

    // single fused f32->bf16 conversion dispatch for x | W_qkv | W_o
    const int c0 = (int)(NX / 4), c1 = (int)(NWQ / 4), c2 = (int)(NWO / 4);
    cvt_all<<<(c0 + c1 + c2) / 256, 256, 0, stream>>>(
        x, Wqkv, Wo, xb, wqkvb, wob, c0, c1, c2);

    // QKV projection: 64 x 12 = 768 blocks = 3 exact rounds at 1 blk/CU
    gemm_nt_128x256<unsigned short><<<dim3(BB * SS / 128, 3 * DD / 256), 512,
                                     98304, stream>>>(xb, wqkvb, qkvb,
                                                      BB * SS, 3 * DD, DD);

    // repack K/V into MFMA-ready fragment-linear tiles
    repack_kv<<<dim3(SS / 64, HH, BB), 256, 0, stream>>>(qkvb, Kp, Vtp);

    // causal MFMA attention (v6 + defer-max)
    attn_mfma6<<<dim3(512), 256, 0, stream>>>(qkvb, Kp, Vtp, headsb);

    // output projection: 64 x 4 = 256 blocks = exactly 1 blk/CU
    gemm_nt_128x256<float><<<dim3(BB * SS / 128, DD / 256), 512, 98304,
                             stream>>>(headsb, wob, out, BB * SS, DD, DD);
}